// Round 5
// baseline (1103.597 us; speedup 1.0000x reference)
//
#include <hip/hip_runtime.h>
#include <hip/hip_bf16.h>
#include <cstdint>
#include <cstddef>

#define NB 16
#define LATD 256
#define DMODEL 256
#define DIN 512
#define DSTATE 16
#define DTRANK 16
#define SEQ 1024
#define KCONV 4
#define NOUT 64
#define NLAYER 4
#define NTOK (NB*SEQ)   // 16384
#define GCH 32          // scan chunks
#define CLEN (SEQ/GCH)  // 32 steps per chunk

typedef __attribute__((ext_vector_type(8))) short short8;
typedef __attribute__((ext_vector_type(4))) float f32x4;

__device__ __forceinline__ float sigmoidf_(float x){ return 1.f/(1.f+__expf(-x)); }
__device__ __forceinline__ short bf16s(float x){ __hip_bfloat16 h = __float2bfloat16(x); return *(short*)&h; }

__device__ __forceinline__ void gl_lds16(const void* g, void* l) {
  __builtin_amdgcn_global_load_lds((const __attribute__((address_space(1))) void*)g,
                                   (__attribute__((address_space(3))) void*)l,
                                   16, 0, 0);
}

// ---------------- latent head: base = gelu(LN(z) @ latent_w.T + latent_bias) ----------------
__global__ void latent_kernel(const float* __restrict__ z,
                              const float* __restrict__ lg, const float* __restrict__ lb,
                              const float* __restrict__ lw, const float* __restrict__ lbias,
                              float* __restrict__ base)
{
  int b = blockIdx.x;          // 16
  int tid = threadIdx.x;       // 256
  __shared__ float zn[LATD];
  __shared__ float red[8];
  float v = z[b*LATD + tid];
  float s = v;
  #pragma unroll
  for (int off=32; off; off>>=1) s += __shfl_xor(s, off);
  if ((tid & 63)==0) red[tid>>6] = s;
  __syncthreads();
  float mu = (red[0]+red[1]+red[2]+red[3]) * (1.f/LATD);
  float dvi = v - mu;
  float s2 = dvi*dvi;
  #pragma unroll
  for (int off=32; off; off>>=1) s2 += __shfl_xor(s2, off);
  if ((tid & 63)==0) red[4 + (tid>>6)] = s2;
  __syncthreads();
  float var = (red[4]+red[5]+red[6]+red[7]) * (1.f/LATD);
  float rs = rsqrtf(var + 1e-5f);
  zn[tid] = dvi*rs*lg[tid] + lb[tid];
  __syncthreads();
  const float* wrow = &lw[(size_t)tid*LATD];
  float acc = lbias[tid];
  #pragma unroll 4
  for (int l=0; l<LATD; ++l) acc += zn[l]*wrow[l];
  float g = 0.5f*acc*(1.f + erff(acc*0.70710678118654752f));   // exact gelu
  base[b*DMODEL + tid] = g;
}

// ---------------- h = base[:,None,:] + time_emb[None] ----------------
__global__ void addtime_kernel(const float* __restrict__ base, const float* __restrict__ temb,
                               float* __restrict__ h)
{
  int idx = blockIdx.x*256 + threadIdx.x;  // over NTOK*DMODEL
  int dd = idx & (DMODEL-1);
  int t = (idx >> 8) & (SEQ-1);
  int bb = idx >> 18;
  h[idx] = base[bb*DMODEL + dd] + temb[t*DMODEL + dd];
}

// ---------------- per-token LayerNorm; 4 tokens/block (1 wave each); OUTBF=1 -> bf16 --------
template<int OUTBF>
__global__ void ln_kernel(const float* __restrict__ x, const float* __restrict__ g,
                          const float* __restrict__ b, void* __restrict__ outp)
{
  int n = blockIdx.x*4 + (threadIdx.x >> 6);
  int lane = threadIdx.x & 63;
  const float4 v = ((const float4*)&x[(size_t)n*DMODEL])[lane];
  float s = v.x+v.y+v.z+v.w;
  #pragma unroll
  for (int off=32; off; off>>=1) s += __shfl_xor(s, off);
  float mu = s * (1.f/DMODEL);
  float dx = v.x-mu, dy = v.y-mu, dz = v.z-mu, dw = v.w-mu;
  float s2 = dx*dx+dy*dy+dz*dz+dw*dw;
  #pragma unroll
  for (int off=32; off; off>>=1) s2 += __shfl_xor(s2, off);
  float rs = rsqrtf(s2*(1.f/DMODEL) + 1e-5f);
  const float4 gv = ((const float4*)g)[lane];
  const float4 bv = ((const float4*)b)[lane];
  float o0 = dx*rs*gv.x + bv.x;
  float o1 = dy*rs*gv.y + bv.y;
  float o2 = dz*rs*gv.z + bv.z;
  float o3 = dw*rs*gv.w + bv.w;
  if (OUTBF) {
    __hip_bfloat16* o = (__hip_bfloat16*)outp + (size_t)n*DMODEL + lane*4;
    o[0] = __float2bfloat16(o0); o[1] = __float2bfloat16(o1);
    o[2] = __float2bfloat16(o2); o[3] = __float2bfloat16(o3);
  } else {
    float4 o; o.x=o0; o.y=o1; o.z=o2; o.w=o3;
    ((float4*)((float*)outp + (size_t)n*DMODEL))[lane] = o;
  }
}

// ---------------- fp32 → bf16 cast ----------------
__global__ void castbf_kernel(const float* __restrict__ in, __hip_bfloat16* __restrict__ out, int n)
{
  int i = blockIdx.x*256 + threadIdx.x;
  if (i < n) out[i] = __float2bfloat16(in[i]);
}

// ---------------- bf16 MFMA GEMM: C[N,M] = A[N,K] @ W[M,K]^T (+bias) (+C if ACCUM) ----------
// 128x128 tile, BK=32, 256 threads (4 waves, each 64x64 via 4x4 mfma_16x16x32 tiles).
template<int ACCUM>
__global__ void gemm_bf16(const __hip_bfloat16* __restrict__ A,
                          const __hip_bfloat16* __restrict__ W,
                          const float* __restrict__ bias, float* __restrict__ C,
                          int N, int M, int K)
{
  __shared__ __hip_bfloat16 As[128*32];   // row-major, 32 bf16 (64B) per row, NO padding
  __shared__ __hip_bfloat16 Ws[128*32];   // (global_load_lds needs lane-contiguous dest)
  int tid = threadIdx.x;
  int lane = tid & 63, w = tid >> 6;
  int wr = w >> 1, wc = w & 1;
  int n0 = blockIdx.x * 128, m0 = blockIdx.y * 128;
  int mrow = lane & 15, q = lane >> 4;
  f32x4 acc[4][4] = {};
  for (int k0 = 0; k0 < K; k0 += 32) {
    __syncthreads();
    #pragma unroll
    for (int j = 0; j < 2; ++j) {
      int c = (w*2 + j)*64 + lane;       // chunk 0..511 of the 8KB tile
      int r = c >> 2, cq = c & 3;        // row, 16B-chunk within row
      gl_lds16(A + (size_t)(n0 + r)*K + k0 + cq*8, (char*)As + (w*2+j)*1024);
      gl_lds16(W + (size_t)(m0 + r)*K + k0 + cq*8, (char*)Ws + (w*2+j)*1024);
    }
    __syncthreads();
    short8 af[4], bfr[4];
    #pragma unroll
    for (int t = 0; t < 4; ++t) {
      af[t]  = *(const short8*)(As + ((wr*64 + t*16 + mrow)*32 + q*8));
      bfr[t] = *(const short8*)(Ws + ((wc*64 + t*16 + mrow)*32 + q*8));
    }
    #pragma unroll
    for (int i = 0; i < 4; ++i)
      #pragma unroll
      for (int jj = 0; jj < 4; ++jj)
        acc[i][jj] = __builtin_amdgcn_mfma_f32_16x16x32_bf16(af[i], bfr[jj], acc[i][jj], 0, 0, 0);
  }
  // epilogue: C/D mapping col=lane&15, row=(lane>>4)*4+reg
  int rq = lane >> 4, cl = lane & 15;
  #pragma unroll
  for (int i = 0; i < 4; ++i) {
    int n_base = n0 + wr*64 + i*16 + rq*4;
    #pragma unroll
    for (int jj = 0; jj < 4; ++jj) {
      int m = m0 + wc*64 + jj*16 + cl;
      float bv = bias ? bias[m] : 0.f;
      #pragma unroll
      for (int r = 0; r < 4; ++r) {
        size_t o = (size_t)(n_base + r)*M + m;
        float v = acc[i][jj][r] + bv;
        if (ACCUM) v += C[o];
        C[o] = v;
      }
    }
  }
}

// ---------------- small-M MFMA GEMM: C[N, MT*16] = A[N, KT*32] @ W^T (+bias) ----------------
template<int MT, int KT>
__global__ void gemm_smallm(const float* __restrict__ A, const __hip_bfloat16* __restrict__ Wg,
                            const float* __restrict__ bias, float* __restrict__ C)
{
  constexpr int M = MT*16, K = KT*32;
  __shared__ __hip_bfloat16 Ws[MT*KT*64*8];
  int tid = threadIdx.x;
  // stage W in exact MFMA B-fragment order: [mt][kt][lane] -> 8 contiguous bf16
  #pragma unroll
  for (int c = tid; c < MT*KT*64; c += 256) {
    int lane = c & 63;
    int kt = (c >> 6) % KT;
    int mt = (c >> 6) / KT;
    int row = mt*16 + (lane & 15);
    int k   = kt*32 + (lane >> 4)*8;
    *(short8*)(Ws + (size_t)c*8) = *(const short8*)(Wg + (size_t)row*K + k);
  }
  __syncthreads();
  int lane = tid & 63, w = tid >> 6;
  int n0 = blockIdx.x*64 + w*16;
  int r = lane & 15, q = lane >> 4;
  const float* Ap = A + (size_t)(n0 + r)*K + q*8;
  f32x4 acc[MT] = {};
  for (int kt = 0; kt < KT; ++kt) {
    float4 a0 = *(const float4*)(Ap);
    float4 a1 = *(const float4*)(Ap + 4);
    Ap += 32;
    short8 af;
    af[0]=bf16s(a0.x); af[1]=bf16s(a0.y); af[2]=bf16s(a0.z); af[3]=bf16s(a0.w);
    af[4]=bf16s(a1.x); af[5]=bf16s(a1.y); af[6]=bf16s(a1.z); af[7]=bf16s(a1.w);
    #pragma unroll
    for (int mt = 0; mt < MT; ++mt) {
      short8 bfr = *(const short8*)(Ws + ((size_t)(mt*KT + kt)*64 + lane)*8);
      acc[mt] = __builtin_amdgcn_mfma_f32_16x16x32_bf16(af, bfr, acc[mt], 0, 0, 0);
    }
  }
  #pragma unroll
  for (int mt = 0; mt < MT; ++mt) {
    float bv = bias ? bias[mt*16 + r] : 0.f;
    #pragma unroll
    for (int rr = 0; rr < 4; ++rr)
      C[(size_t)(n0 + q*4 + rr)*M + mt*16 + r] = acc[mt][rr] + bv;
  }
}

// ---------------- dt projection via K-padded MFMA + fused softplus ----------------
// dt[N,512] = softplus(dbc[:, :16] @ dt_w^T + dt_b). K=16 padded to 32 with zeros.
// 256 threads = 4 waves x 16 tokens; 64 tokens/block; grid = NTOK/64 = 256 blocks.
__global__ void dtproj_kernel(const float* __restrict__ dbc, const float* __restrict__ dtw,
                              const float* __restrict__ dtbias, float* __restrict__ dtout)
{
  __shared__ __hip_bfloat16 Wl[32*64*8];   // 32 KB, B-frag order [mt][lane][8]
  __shared__ float bs[DIN];
  int tid = threadIdx.x;
  for (int c = tid; c < 32*64; c += 256) {
    int lane = c & 63, mt = c >> 6;
    int m = mt*16 + (lane & 15);
    int q = lane >> 4;
    short8 v = {0,0,0,0,0,0,0,0};
    if (q < 2) {
      float4 a0 = *(const float4*)(dtw + m*DTRANK + q*8);
      float4 a1 = *(const float4*)(dtw + m*DTRANK + q*8 + 4);
      v[0]=bf16s(a0.x); v[1]=bf16s(a0.y); v[2]=bf16s(a0.z); v[3]=bf16s(a0.w);
      v[4]=bf16s(a1.x); v[5]=bf16s(a1.y); v[6]=bf16s(a1.z); v[7]=bf16s(a1.w);
    }
    *(short8*)(Wl + (size_t)c*8) = v;
  }
  for (int c = tid; c < DIN; c += 256) bs[c] = dtbias[c];
  __syncthreads();
  int lane = tid & 63, w = tid >> 6;
  int r = lane & 15, q = lane >> 4;
  int n0 = blockIdx.x*64 + w*16;
  short8 af = {0,0,0,0,0,0,0,0};
  if (q < 2) {
    const float* p = dbc + (size_t)(n0 + r)*48 + q*8;
    float4 a0 = *(const float4*)p;
    float4 a1 = *(const float4*)(p + 4);
    af[0]=bf16s(a0.x); af[1]=bf16s(a0.y); af[2]=bf16s(a0.z); af[3]=bf16s(a0.w);
    af[4]=bf16s(a1.x); af[5]=bf16s(a1.y); af[6]=bf16s(a1.z); af[7]=bf16s(a1.w);
  }
  #pragma unroll
  for (int mt = 0; mt < 32; ++mt) {
    short8 bfr = *(const short8*)(Wl + (size_t)(mt*64 + lane)*8);
    f32x4 acc = {0.f,0.f,0.f,0.f};
    acc = __builtin_amdgcn_mfma_f32_16x16x32_bf16(af, bfr, acc, 0, 0, 0);
    float bv = bs[mt*16 + r];
    #pragma unroll
    for (int rr = 0; rr < 4; ++rr) {
      float x = acc[rr] + bv;
      dtout[(size_t)(n0 + q*4 + rr)*DIN + mt*16 + r] = (x > 20.f) ? x : log1pf(__expf(x));
    }
  }
}

// ---------------- depthwise causal conv (K=4) + bias + SiLU ----------------
__global__ void conv_kernel(const float* __restrict__ xz, const float* __restrict__ cw,
                            const float* __restrict__ cb, float* __restrict__ xs)
{
  int idx = blockIdx.x*256 + threadIdx.x; // (n,d) over NTOK*DIN
  int d = idx & (DIN-1);
  int n = idx >> 9;
  int t = n & (SEQ-1);
  const float* w = &cw[d*KCONV];
  float acc = cb[d];
  #pragma unroll
  for (int j = 0; j < KCONV; ++j) {
    if (t - j >= 0) acc = fmaf(xz[(size_t)(n-j)*(2*DIN) + d], w[KCONV-1-j], acc);
  }
  xs[idx] = acc * sigmoidf_(acc);
}

// ================= chunked parallel scan =================
__global__ void scan1_kernel(const float* __restrict__ dt, const float* __restrict__ xs,
                             const float* __restrict__ dbc, const float* __restrict__ Alog,
                             float* __restrict__ hstate, float* __restrict__ xz)
{
  int tid = blockIdx.x*256 + threadIdx.x;  // GCH*NB*DIN = 262144
  int d = tid & (DIN-1);
  int b = (tid >> 9) & (NB-1);
  int g = tid >> 13;
  float a[16], h[16], P[16];
  const float4* A4 = (const float4*)&Alog[d*DSTATE];
  #pragma unroll
  for (int i=0;i<4;++i){
    float4 v = A4[i];
    a[4*i+0]=-__expf(v.x); a[4*i+1]=-__expf(v.y);
    a[4*i+2]=-__expf(v.z); a[4*i+3]=-__expf(v.w);
  }
  #pragma unroll
  for (int s=0;s<16;++s){ h[s]=0.f; P[s]=1.f; }
  int t0 = g*CLEN;
  size_t off  = ((size_t)b*SEQ + t0)*DIN + d;
  size_t boff = ((size_t)b*SEQ + t0)*48;
  for (int t=0;t<CLEN;++t){
    float dtv = dt[off];
    float xv  = xs[off];
    float q = dtv*xv;
    const float4* B4 = (const float4*)&dbc[boff + DTRANK];
    float Bv[16];
    #pragma unroll
    for (int i=0;i<4;++i){ float4 v=B4[i]; Bv[4*i]=v.x; Bv[4*i+1]=v.y; Bv[4*i+2]=v.z; Bv[4*i+3]=v.w; }
    #pragma unroll
    for (int s=0;s<16;++s){
      float p = __expf(dtv*a[s]);
      P[s] *= p;
      h[s] = fmaf(p, h[s], q*Bv[s]);
    }
    off += DIN; boff += 48;
  }
  float4* H4 = (float4*)&hstate[(size_t)tid*16];
  #pragma unroll
  for (int i=0;i<4;++i) H4[i] = make_float4(h[4*i],h[4*i+1],h[4*i+2],h[4*i+3]);
  size_t pbase = (size_t)tid*16;
  #pragma unroll
  for (int s=0;s<16;++s){ size_t i=pbase+s; xz[(i>>9)*1024 + (i&511)] = P[s]; }
}

__global__ void scan2_kernel(float* __restrict__ hstate, const float* __restrict__ xz)
{
  int tid = blockIdx.x*256 + threadIdx.x;  // NB*DIN*16 = 131072
  float hin = 0.f;
  size_t idx = (size_t)tid;
  for (int g=0; g<GCH; ++g){
    float P  = xz[(idx>>9)*1024 + (idx&511)];
    float hl = hstate[idx];
    hstate[idx] = hin;               // becomes initial state for chunk g
    hin = fmaf(P, hin, hl);
    idx += (size_t)NB*DIN*16;
  }
}

__global__ void scan3_kernel(const float* __restrict__ dt, const float* __restrict__ dbc,
                             const float* __restrict__ xz, const float* __restrict__ Alog,
                             const float* __restrict__ Dp, const float* __restrict__ hstate,
                             const float* __restrict__ xs, __hip_bfloat16* __restrict__ yout)
{
  int tid = blockIdx.x*256 + threadIdx.x;  // 262144
  int d = tid & (DIN-1);
  int b = (tid >> 9) & (NB-1);
  int g = tid >> 13;
  float a[16], h[16];
  const float4* A4 = (const float4*)&Alog[d*DSTATE];
  #pragma unroll
  for (int i=0;i<4;++i){
    float4 v = A4[i];
    a[4*i+0]=-__expf(v.x); a[4*i+1]=-__expf(v.y);
    a[4*i+2]=-__expf(v.z); a[4*i+3]=-__expf(v.w);
  }
  const float4* H4 = (const float4*)&hstate[(size_t)tid*16];
  #pragma unroll
  for (int i=0;i<4;++i){ float4 v=H4[i]; h[4*i]=v.x; h[4*i+1]=v.y; h[4*i+2]=v.z; h[4*i+3]=v.w; }
  float dp = Dp[d];
  int t0 = g*CLEN;
  size_t off  = ((size_t)b*SEQ + t0)*DIN + d;
  size_t boff = ((size_t)b*SEQ + t0)*48;
  size_t zoff = ((size_t)b*SEQ + t0)*(2*DIN) + DIN + d;
  for (int t=0;t<CLEN;++t){
    float dtv = dt[off];
    float xv  = xs[off];
    float q = dtv*xv;
    const float4* B4 = (const float4*)&dbc[boff + DTRANK];
    const float4* C4 = (const float4*)&dbc[boff + DTRANK + DSTATE];
    float Bv[16], Cv[16];
    #pragma unroll
    for (int i=0;i<4;++i){
      float4 v=B4[i]; Bv[4*i]=v.x; Bv[4*i+1]=v.y; Bv[4*i+2]=v.z; Bv[4*i+3]=v.w;
      float4 c=C4[i]; Cv[4*i]=c.x; Cv[4*i+1]=c.y; Cv[4*i+2]=c.z; Cv[4*i+3]=c.w;
    }
    float y0=0.f, y1=0.f;
    #pragma unroll
    for (int s=0;s<16;++s){
      float p = __expf(dtv*a[s]);
      h[s] = fmaf(p, h[s], q*Bv[s]);
      if (s & 1) y1 = fmaf(h[s], Cv[s], y1); else y0 = fmaf(h[s], Cv[s], y0);
    }
    float zv = xz[zoff];
    yout[off] = __float2bfloat16(fmaf(xv, dp, y0+y1) * (zv * sigmoidf_(zv)));
    off += DIN; boff += 48; zoff += 2*DIN;
  }
}

extern "C" void kernel_launch(void* const* d_in, const int* in_sizes, int n_in,
                              void* d_out, int out_size, void* d_ws, size_t ws_size,
                              hipStream_t stream)
{
  const float* z           = (const float*)d_in[0];
  const float* latent_g    = (const float*)d_in[1];
  const float* latent_b    = (const float*)d_in[2];
  const float* latent_w    = (const float*)d_in[3];
  const float* latent_bias = (const float*)d_in[4];
  const float* time_emb    = (const float*)d_in[5];
  const float* ln_g        = (const float*)d_in[6];
  const float* ln_b        = (const float*)d_in[7];
  const float* in_w        = (const float*)d_in[8];
  const float* in_b        = (const float*)d_in[9];
  const float* conv_w      = (const float*)d_in[10];
  const float* conv_b      = (const float*)d_in[11];
  const float* xp_w        = (const float*)d_in[12];
  const float* dt_w        = (const float*)d_in[13];
  const float* dt_b        = (const float*)d_in[14];
  const float* A_log       = (const float*)d_in[15];
  const float* Dp          = (const float*)d_in[16];
  const float* out_w       = (const float*)d_in[17];
  const float* out_b       = (const float*)d_in[18];
  const float* on_g        = (const float*)d_in[19];
  const float* on_b        = (const float*)d_in[20];
  const float* op_w        = (const float*)d_in[21];
  const float* op_b        = (const float*)d_in[22];
  float* out = (float*)d_out;

  // workspace layout: ~191 MB
  float* ws   = (float*)d_ws;
  float* base = ws;                                  // 16*256
  float* h    = base + NB*DMODEL;                    // NTOK*256
  float* xn   = h    + (size_t)NTOK*DMODEL;          // NTOK*256 fp32; doubles as: xnbf (bf16 LN out), hstate
  float* xz   = xn   + (size_t)NTOK*DMODEL;          // NTOK*1024 (xc half doubles as pstate)
  float* xsb  = xz   + (size_t)NTOK*2*DIN;           // NTOK*512 fp32 (xs)
  float* dtb  = xsb  + (size_t)NTOK*DIN;             // NTOK*512
  float* dbc  = dtb  + (size_t)NTOK*DIN;             // NTOK*48
  __hip_bfloat16* ybf    = (__hip_bfloat16*)(dbc + (size_t)NTOK*48);   // NTOK*512 bf16
  __hip_bfloat16* inwbf  = ybf + (size_t)NTOK*DIN;                     // 4*1024*256
  __hip_bfloat16* outwbf = inwbf + (size_t)NLAYER*2*DIN*DMODEL;        // 4*256*512
  __hip_bfloat16* xpwbf  = outwbf + (size_t)NLAYER*DMODEL*DIN;         // 4*48*512
  __hip_bfloat16* opwbf  = xpwbf + (size_t)NLAYER*48*DIN;              // 64*256
  __hip_bfloat16* xnbf   = (__hip_bfloat16*)xn;

  // precast weights to bf16 (same work every call)
  castbf_kernel<<<(NLAYER*2*DIN*DMODEL)/256, 256, 0, stream>>>(in_w, inwbf, NLAYER*2*DIN*DMODEL);
  castbf_kernel<<<(NLAYER*DMODEL*DIN)/256, 256, 0, stream>>>(out_w, outwbf, NLAYER*DMODEL*DIN);
  castbf_kernel<<<(NLAYER*48*DIN)/256, 256, 0, stream>>>(xp_w, xpwbf, NLAYER*48*DIN);
  castbf_kernel<<<(NOUT*DMODEL)/256, 256, 0, stream>>>(op_w, opwbf, NOUT*DMODEL);

  latent_kernel<<<NB, 256, 0, stream>>>(z, latent_g, latent_b, latent_w, latent_bias, base);
  addtime_kernel<<<NTOK*DMODEL/256, 256, 0, stream>>>(base, time_emb, h);

  for (int i = 0; i < NLAYER; ++i) {
    ln_kernel<1><<<NTOK/4, 256, 0, stream>>>(h, ln_g + i*DMODEL, ln_b + i*DMODEL, xnbf);
    gemm_bf16<0><<<dim3(NTOK/128, (2*DIN)/128), 256, 0, stream>>>(
        xnbf, inwbf + (size_t)i*2*DIN*DMODEL, in_b + i*2*DIN, xz, NTOK, 2*DIN, DMODEL);
    conv_kernel<<<NTOK*DIN/256, 256, 0, stream>>>(
        xz, conv_w + i*DIN*KCONV, conv_b + i*DIN, xsb);
    gemm_smallm<3, 16><<<NTOK/64, 256, 0, stream>>>(
        xsb, xpwbf + (size_t)i*48*DIN, nullptr, dbc);
    dtproj_kernel<<<NTOK/64, 256, 0, stream>>>(
        dbc, dt_w + (size_t)i*DIN*DTRANK, dt_b + i*DIN, dtb);
    scan1_kernel<<<GCH*NB*DIN/256, 256, 0, stream>>>(
        dtb, xsb, dbc, A_log + (size_t)i*DIN*DSTATE, xn, xz);
    scan2_kernel<<<NB*DIN*16/256, 256, 0, stream>>>(xn, xz);
    scan3_kernel<<<GCH*NB*DIN/256, 256, 0, stream>>>(
        dtb, dbc, xz, A_log + (size_t)i*DIN*DSTATE, Dp + i*DIN, xn, xsb, ybf);
    gemm_bf16<1><<<dim3(NTOK/128, DMODEL/128), 256, 0, stream>>>(
        ybf, outwbf + (size_t)i*DMODEL*DIN, out_b + i*DMODEL, h, NTOK, DMODEL, DIN);
  }

  ln_kernel<0><<<NTOK/4, 256, 0, stream>>>(h, on_g, on_b, xn);
  gemm_smallm<4, 8><<<NTOK/64, 256, 0, stream>>>(xn, opwbf, op_b, out);
}

// Round 6
// 1001.225 us; speedup vs baseline: 1.1022x; 1.1022x over previous
//
#include <hip/hip_runtime.h>
#include <hip/hip_bf16.h>
#include <cstdint>
#include <cstddef>

#define NB 16
#define LATD 256
#define DMODEL 256
#define DIN 512
#define DSTATE 16
#define DTRANK 16
#define SEQ 1024
#define KCONV 4
#define NOUT 64
#define NLAYER 4
#define NTOK (NB*SEQ)   // 16384
#define GCH 32          // scan chunks
#define CLEN (SEQ/GCH)  // 32 steps per chunk

typedef __attribute__((ext_vector_type(8))) short short8;
typedef __attribute__((ext_vector_type(4))) float f32x4;

__device__ __forceinline__ float sigmoidf_(float x){ return 1.f/(1.f+__expf(-x)); }
__device__ __forceinline__ short bf16s(float x){ __hip_bfloat16 h = __float2bfloat16(x); return *(short*)&h; }
__device__ __forceinline__ float softplusf_(float x){ return (x > 20.f) ? x : __logf(1.f + __expf(x)); }

__device__ __forceinline__ void gl_lds16(const void* g, void* l) {
  __builtin_amdgcn_global_load_lds((const __attribute__((address_space(1))) void*)g,
                                   (__attribute__((address_space(3))) void*)l,
                                   16, 0, 0);
}

// ---------------- latent head: base = gelu(LN(z) @ latent_w.T + latent_bias) ----------------
__global__ void latent_kernel(const float* __restrict__ z,
                              const float* __restrict__ lg, const float* __restrict__ lb,
                              const float* __restrict__ lw, const float* __restrict__ lbias,
                              float* __restrict__ base)
{
  int b = blockIdx.x;          // 16
  int tid = threadIdx.x;       // 256
  __shared__ float zn[LATD];
  __shared__ float red[8];
  float v = z[b*LATD + tid];
  float s = v;
  #pragma unroll
  for (int off=32; off; off>>=1) s += __shfl_xor(s, off);
  if ((tid & 63)==0) red[tid>>6] = s;
  __syncthreads();
  float mu = (red[0]+red[1]+red[2]+red[3]) * (1.f/LATD);
  float dvi = v - mu;
  float s2 = dvi*dvi;
  #pragma unroll
  for (int off=32; off; off>>=1) s2 += __shfl_xor(s2, off);
  if ((tid & 63)==0) red[4 + (tid>>6)] = s2;
  __syncthreads();
  float var = (red[4]+red[5]+red[6]+red[7]) * (1.f/LATD);
  float rs = rsqrtf(var + 1e-5f);
  zn[tid] = dvi*rs*lg[tid] + lb[tid];
  __syncthreads();
  const float* wrow = &lw[(size_t)tid*LATD];
  float acc = lbias[tid];
  #pragma unroll 4
  for (int l=0; l<LATD; ++l) acc += zn[l]*wrow[l];
  float g = 0.5f*acc*(1.f + erff(acc*0.70710678118654752f));   // exact gelu
  base[b*DMODEL + tid] = g;
}

// ---------------- h = base[:,None,:] + time_emb[None] ----------------
__global__ void addtime_kernel(const float* __restrict__ base, const float* __restrict__ temb,
                               float* __restrict__ h)
{
  int idx = blockIdx.x*256 + threadIdx.x;  // over NTOK*DMODEL
  int dd = idx & (DMODEL-1);
  int t = (idx >> 8) & (SEQ-1);
  int bb = idx >> 18;
  h[idx] = base[bb*DMODEL + dd] + temb[t*DMODEL + dd];
}

// ---------------- per-token LayerNorm; 4 tokens/block (1 wave each); OUTBF=1 -> bf16 --------
template<int OUTBF>
__global__ void ln_kernel(const float* __restrict__ x, const float* __restrict__ g,
                          const float* __restrict__ b, void* __restrict__ outp)
{
  int n = blockIdx.x*4 + (threadIdx.x >> 6);
  int lane = threadIdx.x & 63;
  const float4 v = ((const float4*)&x[(size_t)n*DMODEL])[lane];
  float s = v.x+v.y+v.z+v.w;
  #pragma unroll
  for (int off=32; off; off>>=1) s += __shfl_xor(s, off);
  float mu = s * (1.f/DMODEL);
  float dx = v.x-mu, dy = v.y-mu, dz = v.z-mu, dw = v.w-mu;
  float s2 = dx*dx+dy*dy+dz*dz+dw*dw;
  #pragma unroll
  for (int off=32; off; off>>=1) s2 += __shfl_xor(s2, off);
  float rs = rsqrtf(s2*(1.f/DMODEL) + 1e-5f);
  const float4 gv = ((const float4*)g)[lane];
  const float4 bv = ((const float4*)b)[lane];
  float o0 = dx*rs*gv.x + bv.x;
  float o1 = dy*rs*gv.y + bv.y;
  float o2 = dz*rs*gv.z + bv.z;
  float o3 = dw*rs*gv.w + bv.w;
  if (OUTBF) {
    __hip_bfloat16* o = (__hip_bfloat16*)outp + (size_t)n*DMODEL + lane*4;
    o[0] = __float2bfloat16(o0); o[1] = __float2bfloat16(o1);
    o[2] = __float2bfloat16(o2); o[3] = __float2bfloat16(o3);
  } else {
    float4 o; o.x=o0; o.y=o1; o.z=o2; o.w=o3;
    ((float4*)((float*)outp + (size_t)n*DMODEL))[lane] = o;
  }
}

// ---------------- fp32 → bf16 cast ----------------
__global__ void castbf_kernel(const float* __restrict__ in, __hip_bfloat16* __restrict__ out, int n)
{
  int i = blockIdx.x*256 + threadIdx.x;
  if (i < n) out[i] = __float2bfloat16(in[i]);
}

// ---------------- bf16 MFMA GEMM: C[N,M] = A[N,K] @ W[M,K]^T (+bias) (+C if ACCUM) ----------
// 128x128 tile, BK=32, 256 threads (4 waves, each 64x64 via 4x4 mfma_16x16x32 tiles).
template<int ACCUM>
__global__ void gemm_bf16(const __hip_bfloat16* __restrict__ A,
                          const __hip_bfloat16* __restrict__ W,
                          const float* __restrict__ bias, float* __restrict__ C,
                          int N, int M, int K)
{
  __shared__ __hip_bfloat16 As[128*32];   // row-major, 32 bf16 (64B) per row, NO padding
  __shared__ __hip_bfloat16 Ws[128*32];   // (global_load_lds needs lane-contiguous dest)
  int tid = threadIdx.x;
  int lane = tid & 63, w = tid >> 6;
  int wr = w >> 1, wc = w & 1;
  int n0 = blockIdx.x * 128, m0 = blockIdx.y * 128;
  int mrow = lane & 15, q = lane >> 4;
  f32x4 acc[4][4] = {};
  for (int k0 = 0; k0 < K; k0 += 32) {
    __syncthreads();
    #pragma unroll
    for (int j = 0; j < 2; ++j) {
      int c = (w*2 + j)*64 + lane;       // chunk 0..511 of the 8KB tile
      int r = c >> 2, cq = c & 3;        // row, 16B-chunk within row
      gl_lds16(A + (size_t)(n0 + r)*K + k0 + cq*8, (char*)As + (w*2+j)*1024);
      gl_lds16(W + (size_t)(m0 + r)*K + k0 + cq*8, (char*)Ws + (w*2+j)*1024);
    }
    __syncthreads();
    short8 af[4], bfr[4];
    #pragma unroll
    for (int t = 0; t < 4; ++t) {
      af[t]  = *(const short8*)(As + ((wr*64 + t*16 + mrow)*32 + q*8));
      bfr[t] = *(const short8*)(Ws + ((wc*64 + t*16 + mrow)*32 + q*8));
    }
    #pragma unroll
    for (int i = 0; i < 4; ++i)
      #pragma unroll
      for (int jj = 0; jj < 4; ++jj)
        acc[i][jj] = __builtin_amdgcn_mfma_f32_16x16x32_bf16(af[i], bfr[jj], acc[i][jj], 0, 0, 0);
  }
  // epilogue: C/D mapping col=lane&15, row=(lane>>4)*4+reg
  int rq = lane >> 4, cl = lane & 15;
  #pragma unroll
  for (int i = 0; i < 4; ++i) {
    int n_base = n0 + wr*64 + i*16 + rq*4;
    #pragma unroll
    for (int jj = 0; jj < 4; ++jj) {
      int m = m0 + wc*64 + jj*16 + cl;
      float bv = bias ? bias[m] : 0.f;
      #pragma unroll
      for (int r = 0; r < 4; ++r) {
        size_t o = (size_t)(n_base + r)*M + m;
        float v = acc[i][jj][r] + bv;
        if (ACCUM) v += C[o];
        C[o] = v;
      }
    }
  }
}

// ---------------- small-M MFMA GEMM: C[N, MT*16] = A[N, KT*32] @ W^T (+bias) ----------------
template<int MT, int KT>
__global__ void gemm_smallm(const float* __restrict__ A, const __hip_bfloat16* __restrict__ Wg,
                            const float* __restrict__ bias, float* __restrict__ C)
{
  constexpr int M = MT*16, K = KT*32;
  __shared__ __hip_bfloat16 Ws[MT*KT*64*8];
  int tid = threadIdx.x;
  // stage W in exact MFMA B-fragment order: [mt][kt][lane] -> 8 contiguous bf16
  #pragma unroll
  for (int c = tid; c < MT*KT*64; c += 256) {
    int lane = c & 63;
    int kt = (c >> 6) % KT;
    int mt = (c >> 6) / KT;
    int row = mt*16 + (lane & 15);
    int k   = kt*32 + (lane >> 4)*8;
    *(short8*)(Ws + (size_t)c*8) = *(const short8*)(Wg + (size_t)row*K + k);
  }
  __syncthreads();
  int lane = tid & 63, w = tid >> 6;
  int n0 = blockIdx.x*64 + w*16;
  int r = lane & 15, q = lane >> 4;
  const float* Ap = A + (size_t)(n0 + r)*K + q*8;
  f32x4 acc[MT] = {};
  for (int kt = 0; kt < KT; ++kt) {
    float4 a0 = *(const float4*)(Ap);
    float4 a1 = *(const float4*)(Ap + 4);
    Ap += 32;
    short8 af;
    af[0]=bf16s(a0.x); af[1]=bf16s(a0.y); af[2]=bf16s(a0.z); af[3]=bf16s(a0.w);
    af[4]=bf16s(a1.x); af[5]=bf16s(a1.y); af[6]=bf16s(a1.z); af[7]=bf16s(a1.w);
    #pragma unroll
    for (int mt = 0; mt < MT; ++mt) {
      short8 bfr = *(const short8*)(Ws + ((size_t)(mt*KT + kt)*64 + lane)*8);
      acc[mt] = __builtin_amdgcn_mfma_f32_16x16x32_bf16(af, bfr, acc[mt], 0, 0, 0);
    }
  }
  #pragma unroll
  for (int mt = 0; mt < MT; ++mt) {
    float bv = bias ? bias[mt*16 + r] : 0.f;
    #pragma unroll
    for (int rr = 0; rr < 4; ++rr)
      C[(size_t)(n0 + q*4 + rr)*M + mt*16 + r] = acc[mt][rr] + bv;
  }
}

// ---------------- depthwise causal conv (K=4) + bias + SiLU ----------------
__global__ void conv_kernel(const float* __restrict__ xz, const float* __restrict__ cw,
                            const float* __restrict__ cb, float* __restrict__ xs)
{
  int idx = blockIdx.x*256 + threadIdx.x; // (n,d) over NTOK*DIN
  int d = idx & (DIN-1);
  int n = idx >> 9;
  int t = n & (SEQ-1);
  const float* w = &cw[d*KCONV];
  float acc = cb[d];
  #pragma unroll
  for (int j = 0; j < KCONV; ++j) {
    if (t - j >= 0) acc = fmaf(xz[(size_t)(n-j)*(2*DIN) + d], w[KCONV-1-j], acc);
  }
  xs[idx] = acc * sigmoidf_(acc);
}

// ================= chunked parallel scan (dt-projection fused) =================
// dt[n,d] = softplus(dot16(dbc[n,:16], dtw[d,:]) + dtb[d]) computed inline in both passes.
__global__ void scan1_kernel(const float* __restrict__ xs, const float* __restrict__ dbc,
                             const float* __restrict__ Alog,
                             const float* __restrict__ dtw, const float* __restrict__ dtbias,
                             float* __restrict__ hstate, float* __restrict__ xz)
{
  int tid = blockIdx.x*256 + threadIdx.x;  // GCH*NB*DIN = 262144
  int d = tid & (DIN-1);
  int b = (tid >> 9) & (NB-1);
  int g = tid >> 13;
  float a[16], h[16], P[16], wdt[16];
  const float4* A4 = (const float4*)&Alog[d*DSTATE];
  const float4* W4 = (const float4*)&dtw[d*DTRANK];
  #pragma unroll
  for (int i=0;i<4;++i){
    float4 v = A4[i];
    a[4*i+0]=-__expf(v.x); a[4*i+1]=-__expf(v.y);
    a[4*i+2]=-__expf(v.z); a[4*i+3]=-__expf(v.w);
    float4 wv = W4[i];
    wdt[4*i]=wv.x; wdt[4*i+1]=wv.y; wdt[4*i+2]=wv.z; wdt[4*i+3]=wv.w;
  }
  float bdt = dtbias[d];
  #pragma unroll
  for (int s=0;s<16;++s){ h[s]=0.f; P[s]=1.f; }
  int t0 = g*CLEN;
  size_t off  = ((size_t)b*SEQ + t0)*DIN + d;
  size_t boff = ((size_t)b*SEQ + t0)*48;
  for (int t=0;t<CLEN;++t){
    float xv = xs[off];
    const float4* R4 = (const float4*)&dbc[boff];
    float acc = bdt;
    #pragma unroll
    for (int i=0;i<4;++i){
      float4 v = R4[i];
      acc = fmaf(v.x, wdt[4*i], acc); acc = fmaf(v.y, wdt[4*i+1], acc);
      acc = fmaf(v.z, wdt[4*i+2], acc); acc = fmaf(v.w, wdt[4*i+3], acc);
    }
    float dtv = softplusf_(acc);
    float q = dtv*xv;
    const float4* B4 = (const float4*)&dbc[boff + DTRANK];
    float Bv[16];
    #pragma unroll
    for (int i=0;i<4;++i){ float4 v=B4[i]; Bv[4*i]=v.x; Bv[4*i+1]=v.y; Bv[4*i+2]=v.z; Bv[4*i+3]=v.w; }
    #pragma unroll
    for (int s=0;s<16;++s){
      float p = __expf(dtv*a[s]);
      P[s] *= p;
      h[s] = fmaf(p, h[s], q*Bv[s]);
    }
    off += DIN; boff += 48;
  }
  float4* H4 = (float4*)&hstate[(size_t)tid*16];
  #pragma unroll
  for (int i=0;i<4;++i) H4[i] = make_float4(h[4*i],h[4*i+1],h[4*i+2],h[4*i+3]);
  size_t pbase = (size_t)tid*16;
  #pragma unroll
  for (int s=0;s<16;++s){ size_t i=pbase+s; xz[(i>>9)*1024 + (i&511)] = P[s]; }
}

__global__ void scan2_kernel(float* __restrict__ hstate, const float* __restrict__ xz)
{
  int tid = blockIdx.x*256 + threadIdx.x;  // NB*DIN*16 = 131072
  float hin = 0.f;
  size_t idx = (size_t)tid;
  for (int g=0; g<GCH; ++g){
    float P  = xz[(idx>>9)*1024 + (idx&511)];
    float hl = hstate[idx];
    hstate[idx] = hin;               // becomes initial state for chunk g
    hin = fmaf(P, hin, hl);
    idx += (size_t)NB*DIN*16;
  }
}

__global__ void scan3_kernel(const float* __restrict__ dbc, const float* __restrict__ xz,
                             const float* __restrict__ Alog,
                             const float* __restrict__ dtw, const float* __restrict__ dtbias,
                             const float* __restrict__ Dp, const float* __restrict__ hstate,
                             const float* __restrict__ xs, __hip_bfloat16* __restrict__ yout)
{
  int tid = blockIdx.x*256 + threadIdx.x;  // 262144
  int d = tid & (DIN-1);
  int b = (tid >> 9) & (NB-1);
  int g = tid >> 13;
  float a[16], h[16], wdt[16];
  const float4* A4 = (const float4*)&Alog[d*DSTATE];
  const float4* W4 = (const float4*)&dtw[d*DTRANK];
  #pragma unroll
  for (int i=0;i<4;++i){
    float4 v = A4[i];
    a[4*i+0]=-__expf(v.x); a[4*i+1]=-__expf(v.y);
    a[4*i+2]=-__expf(v.z); a[4*i+3]=-__expf(v.w);
    float4 wv = W4[i];
    wdt[4*i]=wv.x; wdt[4*i+1]=wv.y; wdt[4*i+2]=wv.z; wdt[4*i+3]=wv.w;
  }
  float bdt = dtbias[d];
  const float4* H4 = (const float4*)&hstate[(size_t)tid*16];
  #pragma unroll
  for (int i=0;i<4;++i){ float4 v=H4[i]; h[4*i]=v.x; h[4*i+1]=v.y; h[4*i+2]=v.z; h[4*i+3]=v.w; }
  float dp = Dp[d];
  int t0 = g*CLEN;
  size_t off  = ((size_t)b*SEQ + t0)*DIN + d;
  size_t boff = ((size_t)b*SEQ + t0)*48;
  size_t zoff = ((size_t)b*SEQ + t0)*(2*DIN) + DIN + d;
  for (int t=0;t<CLEN;++t){
    float xv = xs[off];
    const float4* R4 = (const float4*)&dbc[boff];
    float acc = bdt;
    #pragma unroll
    for (int i=0;i<4;++i){
      float4 v = R4[i];
      acc = fmaf(v.x, wdt[4*i], acc); acc = fmaf(v.y, wdt[4*i+1], acc);
      acc = fmaf(v.z, wdt[4*i+2], acc); acc = fmaf(v.w, wdt[4*i+3], acc);
    }
    float dtv = softplusf_(acc);
    float q = dtv*xv;
    const float4* B4 = (const float4*)&dbc[boff + DTRANK];
    const float4* C4 = (const float4*)&dbc[boff + DTRANK + DSTATE];
    float Bv[16], Cv[16];
    #pragma unroll
    for (int i=0;i<4;++i){
      float4 v=B4[i]; Bv[4*i]=v.x; Bv[4*i+1]=v.y; Bv[4*i+2]=v.z; Bv[4*i+3]=v.w;
      float4 c=C4[i]; Cv[4*i]=c.x; Cv[4*i+1]=c.y; Cv[4*i+2]=c.z; Cv[4*i+3]=c.w;
    }
    float y0=0.f, y1=0.f;
    #pragma unroll
    for (int s=0;s<16;++s){
      float p = __expf(dtv*a[s]);
      h[s] = fmaf(p, h[s], q*Bv[s]);
      if (s & 1) y1 = fmaf(h[s], Cv[s], y1); else y0 = fmaf(h[s], Cv[s], y0);
    }
    float zv = xz[zoff];
    yout[off] = __float2bfloat16(fmaf(xv, dp, y0+y1) * (zv * sigmoidf_(zv)));
    off += DIN; boff += 48; zoff += 2*DIN;
  }
}

extern "C" void kernel_launch(void* const* d_in, const int* in_sizes, int n_in,
                              void* d_out, int out_size, void* d_ws, size_t ws_size,
                              hipStream_t stream)
{
  const float* z           = (const float*)d_in[0];
  const float* latent_g    = (const float*)d_in[1];
  const float* latent_b    = (const float*)d_in[2];
  const float* latent_w    = (const float*)d_in[3];
  const float* latent_bias = (const float*)d_in[4];
  const float* time_emb    = (const float*)d_in[5];
  const float* ln_g        = (const float*)d_in[6];
  const float* ln_b        = (const float*)d_in[7];
  const float* in_w        = (const float*)d_in[8];
  const float* in_b        = (const float*)d_in[9];
  const float* conv_w      = (const float*)d_in[10];
  const float* conv_b      = (const float*)d_in[11];
  const float* xp_w        = (const float*)d_in[12];
  const float* dt_w        = (const float*)d_in[13];
  const float* dt_b        = (const float*)d_in[14];
  const float* A_log       = (const float*)d_in[15];
  const float* Dp          = (const float*)d_in[16];
  const float* out_w       = (const float*)d_in[17];
  const float* out_b       = (const float*)d_in[18];
  const float* on_g        = (const float*)d_in[19];
  const float* on_b        = (const float*)d_in[20];
  const float* op_w        = (const float*)d_in[21];
  const float* op_b        = (const float*)d_in[22];
  float* out = (float*)d_out;

  // workspace layout: ~191 MB
  float* ws   = (float*)d_ws;
  float* base = ws;                                  // 16*256
  float* h    = base + NB*DMODEL;                    // NTOK*256
  float* xn   = h    + (size_t)NTOK*DMODEL;          // NTOK*256 fp32; doubles as: xnbf (bf16 LN out), hstate
  float* xz   = xn   + (size_t)NTOK*DMODEL;          // NTOK*1024 (xc half doubles as pstate)
  float* xsb  = xz   + (size_t)NTOK*2*DIN;           // NTOK*512 fp32 (xs)
  float* dtb  = xsb  + (size_t)NTOK*DIN;             // NTOK*512 (now unused; kept for layout stability)
  float* dbc  = dtb  + (size_t)NTOK*DIN;             // NTOK*48
  __hip_bfloat16* ybf    = (__hip_bfloat16*)(dbc + (size_t)NTOK*48);   // NTOK*512 bf16
  __hip_bfloat16* inwbf  = ybf + (size_t)NTOK*DIN;                     // 4*1024*256
  __hip_bfloat16* outwbf = inwbf + (size_t)NLAYER*2*DIN*DMODEL;        // 4*256*512
  __hip_bfloat16* xpwbf  = outwbf + (size_t)NLAYER*DMODEL*DIN;         // 4*48*512
  __hip_bfloat16* opwbf  = xpwbf + (size_t)NLAYER*48*DIN;              // 64*256
  __hip_bfloat16* xnbf   = (__hip_bfloat16*)xn;

  // precast weights to bf16 (same work every call)
  castbf_kernel<<<(NLAYER*2*DIN*DMODEL)/256, 256, 0, stream>>>(in_w, inwbf, NLAYER*2*DIN*DMODEL);
  castbf_kernel<<<(NLAYER*DMODEL*DIN)/256, 256, 0, stream>>>(out_w, outwbf, NLAYER*DMODEL*DIN);
  castbf_kernel<<<(NLAYER*48*DIN)/256, 256, 0, stream>>>(xp_w, xpwbf, NLAYER*48*DIN);
  castbf_kernel<<<(NOUT*DMODEL)/256, 256, 0, stream>>>(op_w, opwbf, NOUT*DMODEL);

  latent_kernel<<<NB, 256, 0, stream>>>(z, latent_g, latent_b, latent_w, latent_bias, base);
  addtime_kernel<<<NTOK*DMODEL/256, 256, 0, stream>>>(base, time_emb, h);

  for (int i = 0; i < NLAYER; ++i) {
    ln_kernel<1><<<NTOK/4, 256, 0, stream>>>(h, ln_g + i*DMODEL, ln_b + i*DMODEL, xnbf);
    gemm_bf16<0><<<dim3(NTOK/128, (2*DIN)/128), 256, 0, stream>>>(
        xnbf, inwbf + (size_t)i*2*DIN*DMODEL, in_b + i*2*DIN, xz, NTOK, 2*DIN, DMODEL);
    conv_kernel<<<NTOK*DIN/256, 256, 0, stream>>>(
        xz, conv_w + i*DIN*KCONV, conv_b + i*DIN, xsb);
    gemm_smallm<3, 16><<<NTOK/64, 256, 0, stream>>>(
        xsb, xpwbf + (size_t)i*48*DIN, nullptr, dbc);
    scan1_kernel<<<GCH*NB*DIN/256, 256, 0, stream>>>(
        xsb, dbc, A_log + (size_t)i*DIN*DSTATE,
        dt_w + (size_t)i*DIN*DTRANK, dt_b + i*DIN, xn, xz);
    scan2_kernel<<<NB*DIN*16/256, 256, 0, stream>>>(xn, xz);
    scan3_kernel<<<GCH*NB*DIN/256, 256, 0, stream>>>(
        dbc, xz, A_log + (size_t)i*DIN*DSTATE,
        dt_w + (size_t)i*DIN*DTRANK, dt_b + i*DIN, Dp + i*DIN, xn, xsb, ybf);
    gemm_bf16<1><<<dim3(NTOK/128, DMODEL/128), 256, 0, stream>>>(
        ybf, outwbf + (size_t)i*DMODEL*DIN, out_b + i*DMODEL, h, NTOK, DMODEL, DIN);
  }

  ln_kernel<0><<<NTOK/4, 256, 0, stream>>>(h, on_g, on_b, xn);
  gemm_smallm<4, 8><<<NTOK/64, 256, 0, stream>>>(xn, opwbf, op_b, out);
}